// Round 10
// baseline (259.918 us; speedup 1.0000x reference)
//
#include <hip/hip_runtime.h>

// MultiHeadAttention: B=2, S=4096, D=512, H=8, depth=64. fp32 in/out.
// mfma_f32_16x16x32_f16 everywhere, fp32 accum. S^T = K Q^T flash (one q-row
// per lane), async double-buffered staging in ALL matmul kernels.
// Round 21: reverted NSPL to 2 (R9's x4 gained flash -4us but cost +8us in
// combine/partial traffic). cvt_qkv ELIMINATED: proj3 now reg-stages X
// straight from the fp32 inputs (float4 loads issued post-barrier, packed
// with cvt_pkrtz + ds_write_b128 post-compute -- T14 issue-early/write-late;
// identical LDS swizzle + rounding, so numerics unchanged). Kills a 75MB
// round-trip kernel. Flash: QBLK=32, wave-private P-LDS, XCD-bijective
// swizzle, mask reg-prefetch, defer-max (THR=8, lane-local), v_max3 tree,
// dot2 psum -- R8 verbatim (best measured: flash 120us, FETCH 16.5MB).
#define NH   8
#define DH   64
#define NB   2
#define SEQ  4096
#define DM   512
#define MR   (NB * SEQ)
#define LSTR 72
#define LOG2E 1.44269504089f
#define NSPL 2
#define KVS  (SEQ / NSPL)
#define RH   (NB * NH * SEQ)   // 65536 q-rows across heads/splits
#define PSTR 36                // P_lds row stride in u32 (even, mult of 4)

using f16x8 = __attribute__((ext_vector_type(8))) _Float16;
using f32x4 = __attribute__((ext_vector_type(4))) float;
using h2    = __attribute__((ext_vector_type(2))) _Float16;
#define MFMA16(a, b, c) __builtin_amdgcn_mfma_f32_16x16x32_f16(a, b, c, 0, 0, 0)

#if defined(__has_builtin) && __has_builtin(__builtin_amdgcn_exp2f)
#define EXP2(x) __builtin_amdgcn_exp2f(x)
#else
extern "C" __device__ float __ocml_native_exp2_f32(float);
#define EXP2(x) __ocml_native_exp2_f32(x)
#endif

__device__ __forceinline__ unsigned pk_f16(float a, float b) {
    typedef __fp16 fp16v2 __attribute__((ext_vector_type(2)));
    union { fp16v2 h; unsigned u; } c;
    c.h = __builtin_amdgcn_cvt_pkrtz(a, b);
    return c.u;
}
__device__ __forceinline__ float m3(float a, float b, float c) {
    return fmaxf(fmaxf(a, b), c);   // fuses to v_max3_f32
}
// l-sum accumulate from a packed f16 pair: c += p.lo + p.hi
__device__ __forceinline__ float dot2acc(unsigned u, float c) {
#if defined(__has_builtin) && __has_builtin(__builtin_amdgcn_fdot2)
    h2 a = __builtin_bit_cast(h2, u);
    h2 one = {(_Float16)1.f, (_Float16)1.f};
    return __builtin_amdgcn_fdot2(a, one, c, false);
#else
    h2 a = __builtin_bit_cast(h2, u);
    return c + (float)a[0] + (float)a[1];
#endif
}
// async 16B/lane global -> LDS (lds dest = wave-uniform base + lane*16)
__device__ __forceinline__ void async16(void* lds, const void* g) {
    __builtin_amdgcn_global_load_lds(
        (__attribute__((address_space(1))) void*)g,
        (__attribute__((address_space(3))) void*)lds, 16, 0, 0);
}

// ---------------------------------------------------------------------------
// W fp32 [k][n] -> Wt f16 [n][k], 4 weights. grid (8,8,4) x 256.
// ---------------------------------------------------------------------------
__global__ __launch_bounds__(256) void cvt_w(
    const float* __restrict__ w0, const float* __restrict__ w1,
    const float* __restrict__ w2, const float* __restrict__ w3,
    _Float16* __restrict__ Wt)
{
    __shared__ _Float16 T[64 * LSTR];
    const int z = blockIdx.z;
    const float* W = (z == 0) ? w0 : (z == 1 ? w1 : (z == 2 ? w2 : w3));
    _Float16* out = Wt + (size_t)z * DM * DM;
    const int t = threadIdx.x;
    const int k0 = blockIdx.x * 64, n0 = blockIdx.y * 64;
#pragma unroll
    for (int i = 0; i < 4; ++i) {
        const int kl  = i * 16 + (t >> 4);
        const int nl4 = (t & 15) * 4;
        float4 u = *(const float4*)(W + (size_t)(k0 + kl) * DM + n0 + nl4);
        T[(nl4 + 0) * LSTR + kl] = (_Float16)u.x;
        T[(nl4 + 1) * LSTR + kl] = (_Float16)u.y;
        T[(nl4 + 2) * LSTR + kl] = (_Float16)u.z;
        T[(nl4 + 3) * LSTR + kl] = (_Float16)u.w;
    }
    __syncthreads();
#pragma unroll
    for (int i = 0; i < 2; ++i) {
        const int nl = i * 32 + (t >> 3);
        const int kc = (t & 7) * 8;
        *(uint4*)(out + (size_t)(n0 + nl) * DM + k0 + kc) = *(const uint4*)&T[nl * LSTR + kc];
    }
}

// mask [B,1,1,S] fp32 -> mw = mask * (-1e9*log2e). grid 32 x 256.
__global__ __launch_bounds__(256) void maskprep(const float* __restrict__ mask,
                                                float* __restrict__ mw)
{
    const int i = blockIdx.x * 256 + threadIdx.x;
    mw[i] = mask[i] * (-1e9f * LOG2E);
}

// ---------------------------------------------------------------------------
// Fused QKV projection, async double-buffered, fp32 X inputs (conversion
// fused into staging: float4 loads issued post-barrier, cvt_pkrtz packed +
// ds_write_b128 post-compute). Wt f16 [3][n][k] via global_load_lds.
// z<2: head-split f16 [B,H,S,64] (Q scaled by log2e); z==2: transposed
// [B,H,64,S]. grid (MR/128, 8, 3), block 256. LDS swizzle: chunk c ->
// row c>>3, slot c&7; data for column-chunk ((c&7)^(row&7)) stored there
// (swizzle applied on the global address side).
// ---------------------------------------------------------------------------
__global__ __launch_bounds__(256) void proj3(
    const float* __restrict__ Qf, const float* __restrict__ Kf,
    const float* __restrict__ Vf, const _Float16* __restrict__ Wt,
    const float* __restrict__ bq, const float* __restrict__ bk,
    const float* __restrict__ bv,
    _Float16* __restrict__ Qo, _Float16* __restrict__ Ko,
    _Float16* __restrict__ VTo)
{
    __shared__ _Float16 Xs[2][128 * 64];
    __shared__ _Float16 Ws[2][64 * 64];

    const int z = blockIdx.z;
    const float* X = (z == 0) ? Qf : (z == 1 ? Kf : Vf);
    const _Float16* W = Wt + (size_t)z * DM * DM;
    const float* bias = (z == 0) ? bq : (z == 1 ? bk : bv);
    const float scale = (z == 0) ? LOG2E : 1.0f;

    const int t = threadIdx.x;
    const int l = t & 63, w = t >> 6;
    const int m = l & 15, g = l >> 4;
    const int ms = m & 7;
    const int row0 = blockIdx.x * 128;
    const int col0 = blockIdx.y * 64;

    int xr[4], xsw[4], xc[4];
#pragma unroll
    for (int i = 0; i < 4; ++i) {
        const int c = w * 256 + i * 64 + l;
        xr[i]  = c >> 3;
        xsw[i] = ((c & 7) ^ (xr[i] & 7)) * 8;
        xc[i]  = c * 8;            // LDS elem offset of this lane's chunk
    }
    int wr[2], wsw[2];
#pragma unroll
    for (int i = 0; i < 2; ++i) {
        const int c = w * 128 + i * 64 + l;
        wr[i]  = c >> 3;
        wsw[i] = ((c & 7) ^ (wr[i] & 7)) * 8;
    }

    // prologue: k0 = 0 into buffer 0 (X via reg-stage, W via async16)
    {
        float4 xa[4], xb[4];
#pragma unroll
        for (int i = 0; i < 4; ++i) {
            const float* src = X + (size_t)(row0 + xr[i]) * DM + xsw[i];
            xa[i] = *(const float4*)src;
            xb[i] = *(const float4*)(src + 4);
        }
#pragma unroll
        for (int i = 0; i < 2; ++i)
            async16(&Ws[0][(w * 128 + i * 64) * 8], W + (size_t)(col0 + wr[i]) * DM + wsw[i]);
#pragma unroll
        for (int i = 0; i < 4; ++i)
            *(uint4*)&Xs[0][xc[i]] = make_uint4(
                pk_f16(xa[i].x, xa[i].y), pk_f16(xa[i].z, xa[i].w),
                pk_f16(xb[i].x, xb[i].y), pk_f16(xb[i].z, xb[i].w));
    }

    f32x4 acc[2][4] = {};

    for (int k0 = 0; k0 < DM; k0 += 64) {
        const int p = (k0 >> 6) & 1;
        __syncthreads();   // publishes buffer p (X ds_writes + W async16)

        float4 xa[4], xb[4];
        const bool more = (k0 + 64 < DM);
        if (more) {
            const int kn = k0 + 64;
#pragma unroll
            for (int i = 0; i < 4; ++i) {
                const float* src = X + (size_t)(row0 + xr[i]) * DM + kn + xsw[i];
                xa[i] = *(const float4*)src;
                xb[i] = *(const float4*)(src + 4);
            }
#pragma unroll
            for (int i = 0; i < 2; ++i)
                async16(&Ws[p ^ 1][(w * 128 + i * 64) * 8],
                        W + (size_t)(col0 + wr[i]) * DM + kn + wsw[i]);
        }
#pragma unroll
        for (int kk = 0; kk < 2; ++kk) {
            const int slot = ((kk * 4 + g) ^ ms) * 8;
            f16x8 a0 = *(const f16x8*)&Xs[p][(w * 32 + m) * 64 + slot];
            f16x8 a1 = *(const f16x8*)&Xs[p][(w * 32 + 16 + m) * 64 + slot];
#pragma unroll
            for (int ct = 0; ct < 4; ++ct) {
                f16x8 bf = *(const f16x8*)&Ws[p][(ct * 16 + m) * 64 + slot];
                acc[0][ct] = MFMA16(a0, bf, acc[0][ct]);
                acc[1][ct] = MFMA16(a1, bf, acc[1][ct]);
            }
        }
        if (more) {
#pragma unroll
            for (int i = 0; i < 4; ++i)
                *(uint4*)&Xs[p ^ 1][xc[i]] = make_uint4(
                    pk_f16(xa[i].x, xa[i].y), pk_f16(xa[i].z, xa[i].w),
                    pk_f16(xb[i].x, xb[i].y), pk_f16(xb[i].z, xb[i].w));
        }
    }

    float bv4[4];
#pragma unroll
    for (int ct = 0; ct < 4; ++ct) bv4[ct] = bias[col0 + ct * 16 + m];

    if (z == 2) {
        __syncthreads();   // all waves done reading Xs
        _Float16* T = &Xs[0][0];   // reuse as T[64][136]
#pragma unroll
        for (int rt = 0; rt < 2; ++rt)
#pragma unroll
            for (int reg = 0; reg < 4; ++reg) {
                const int s_l = w * 32 + rt * 16 + g * 4 + reg;
#pragma unroll
                for (int ct = 0; ct < 4; ++ct) {
                    const int d = ct * 16 + m;
                    T[d * 136 + s_l] = (_Float16)(acc[rt][ct][reg] + bv4[ct]);
                }
            }
        __syncthreads();
        const int bb = row0 >> 12;
        const int s0 = row0 & (SEQ - 1);
#pragma unroll
        for (int j = 0; j < 4; ++j) {
            const int c = j * 256 + t;
            const int d = c >> 4;
            const int sc = (c & 15) * 8;
            *(uint4*)(VTo + (((size_t)bb * NH + blockIdx.y) * DH + d) * SEQ + s0 + sc) =
                *(const uint4*)&T[d * 136 + sc];
        }
    } else {
        _Float16* out = (z == 0) ? Qo : Ko;
#pragma unroll
        for (int rt = 0; rt < 2; ++rt)
#pragma unroll
            for (int reg = 0; reg < 4; ++reg) {
                const int row = row0 + w * 32 + rt * 16 + g * 4 + reg;
                const int bb = row >> 12;
                const int s  = row & (SEQ - 1);
#pragma unroll
                for (int ct = 0; ct < 4; ++ct)
                    out[(((size_t)bb * NH + blockIdx.y) * SEQ + s) * DH + ct * 16 + m] =
                        (_Float16)(scale * (acc[rt][ct][reg] + bv4[ct]));
            }
    }
}

// ---------------------------------------------------------------------------
// Output GEMM: d_out[M,512] fp32 = Ows[M,512](f16) @ Wo + bo. Async dbuf.
// grid (MR/128, 8), block 256.
// ---------------------------------------------------------------------------
__global__ __launch_bounds__(256) void gemm_out(const _Float16* __restrict__ X,
                                                const _Float16* __restrict__ W,
                                                const float* __restrict__ bias,
                                                float* __restrict__ out)
{
    __shared__ _Float16 Xs[2][128 * 64];
    __shared__ _Float16 Ws[2][64 * 64];

    const int t = threadIdx.x;
    const int l = t & 63, w = t >> 6;
    const int m = l & 15, g = l >> 4;
    const int ms = m & 7;
    const int row0 = blockIdx.x * 128;
    const int col0 = blockIdx.y * 64;

    int xr[4], xsw[4];
#pragma unroll
    for (int i = 0; i < 4; ++i) {
        const int c = w * 256 + i * 64 + l;
        xr[i]  = c >> 3;
        xsw[i] = ((c & 7) ^ (xr[i] & 7)) * 8;
    }
    int wr[2], wsw[2];
#pragma unroll
    for (int i = 0; i < 2; ++i) {
        const int c = w * 128 + i * 64 + l;
        wr[i]  = c >> 3;
        wsw[i] = ((c & 7) ^ (wr[i] & 7)) * 8;
    }

#pragma unroll
    for (int i = 0; i < 4; ++i)
        async16(&Xs[0][(w * 256 + i * 64) * 8], X + (size_t)(row0 + xr[i]) * DM + xsw[i]);
#pragma unroll
    for (int i = 0; i < 2; ++i)
        async16(&Ws[0][(w * 128 + i * 64) * 8], W + (size_t)(col0 + wr[i]) * DM + wsw[i]);

    f32x4 acc[2][4] = {};

    for (int k0 = 0; k0 < DM; k0 += 64) {
        const int p = (k0 >> 6) & 1;
        __syncthreads();
        if (k0 + 64 < DM) {
            const int kn = k0 + 64;
#pragma unroll
            for (int i = 0; i < 4; ++i)
                async16(&Xs[p ^ 1][(w * 256 + i * 64) * 8],
                        X + (size_t)(row0 + xr[i]) * DM + kn + xsw[i]);
#pragma unroll
            for (int i = 0; i < 2; ++i)
                async16(&Ws[p ^ 1][(w * 128 + i * 64) * 8],
                        W + (size_t)(col0 + wr[i]) * DM + kn + wsw[i]);
        }
#pragma unroll
        for (int kk = 0; kk < 2; ++kk) {
            const int slot = ((kk * 4 + g) ^ ms) * 8;
            f16x8 a0 = *(const f16x8*)&Xs[p][(w * 32 + m) * 64 + slot];
            f16x8 a1 = *(const f16x8*)&Xs[p][(w * 32 + 16 + m) * 64 + slot];
#pragma unroll
            for (int ct = 0; ct < 4; ++ct) {
                f16x8 bf = *(const f16x8*)&Ws[p][(ct * 16 + m) * 64 + slot];
                acc[0][ct] = MFMA16(a0, bf, acc[0][ct]);
                acc[1][ct] = MFMA16(a1, bf, acc[1][ct]);
            }
        }
    }

    float bv4[4];
#pragma unroll
    for (int ct = 0; ct < 4; ++ct) bv4[ct] = bias[col0 + ct * 16 + m];

#pragma unroll
    for (int rt = 0; rt < 2; ++rt)
#pragma unroll
        for (int reg = 0; reg < 4; ++reg) {
            const int row = row0 + w * 32 + rt * 16 + g * 4 + reg;
#pragma unroll
            for (int ct = 0; ct < 4; ++ct)
                out[(size_t)row * DM + col0 + ct * 16 + m] = acc[rt][ct][reg] + bv4[ct];
        }
}

// ---------------------------------------------------------------------------
// Flash attention, KV-split x2, 32 q-rows per wave (two 16-row halves).
// Q(log2e-scaled),K f16 [B*H,S,64]; VT f16 [B*H,64,S]; mw fp32 [B][S]
// (pre-scaled mask, MFMA C-init, register-prefetched one tile ahead).
// Split z covers kv in [z*2048, z*2048+2048); writes per-split-NORMALIZED
// partial Op f16 [z][bh][q][64] plus Ml f32x2 {m,l}. grid (S/128, B*H, 2)
// with XCD-bijective swizzle: flat w -> o=(w&7)*128 + w>>3, so the 32
// q-blocks sharing one (bh,z) K/V panel (512KB, L2-resident) run on ONE
// XCD. Every K/V LDS fragment read feeds TWO MFMAs (one per q-half); PV
// B-frags via wave-private P staging in LDS. __launch_bounds__(256,3).
// ---------------------------------------------------------------------------
__global__ __launch_bounds__(256, 3) void flash_mfma(
    const _Float16* __restrict__ Q, const _Float16* __restrict__ K,
    const _Float16* __restrict__ VT, const float* __restrict__ mw,
    _Float16* __restrict__ Op, float* __restrict__ Ml)
{
    __shared__ _Float16 Ks [2][64 * 64];
    __shared__ _Float16 VTs[2][64 * 64];
    __shared__ unsigned Ps[4][32 * PSTR];   // per-wave P pairs: [q-row][pair]

    const int t = threadIdx.x;
    const int l = t & 63, w = t >> 6;
    const int m = l & 15, g = l >> 4;

    // XCD-bijective swizzle (1024 blocks, 1024 % 8 == 0)
    const unsigned wfl = blockIdx.x + 32u * blockIdx.y + 512u * blockIdx.z;
    const unsigned o   = (wfl & 7u) * 128u + (wfl >> 3);
    const int q0 = (int)(o & 31u) * 128;
    const int bh = (int)(o >> 5) & 15;
    const int z  = (int)(o >> 9);
    const int b  = bh >> 3;
    const int kb0 = z * KVS;

    const _Float16* Qh  = Q  + (size_t)bh * SEQ * DH;
    const _Float16* Kh  = K  + (size_t)bh * SEQ * DH;
    const _Float16* VTh = VT + (size_t)bh * DH * SEQ;
    const float* mwb = mw + (size_t)b * SEQ;

    const int c0 = w * 128 + l, c1 = c0 + 64;
    const int r0 = c0 >> 3,     r1 = c1 >> 3;
    const int cl0 = (c0 & 7) ^ (r0 & 7), cl1 = (c1 & 7) ^ (r1 & 7);
    const int    gK0 = r0 * DH + cl0 * 8, gK1 = r1 * DH + cl1 * 8;
    const size_t gV0 = (size_t)r0 * SEQ + cl0 * 8, gV1 = (size_t)r1 * SEQ + cl1 * 8;
    const int ldsA = w * 1024, ldsB = ldsA + 512;

    async16(&Ks[0][ldsA], Kh + (size_t)kb0 * DH + gK0);
    async16(&Ks[0][ldsB], Kh + (size_t)kb0 * DH + gK1);
    async16(&VTs[0][ldsA], VTh + kb0 + gV0);
    async16(&VTs[0][ldsB], VTh + kb0 + gV1);

    // Q fragments in registers: wave w covers q-rows q0 + w*32 + {0..15,16..31}
    f16x8 qf[2][2];
#pragma unroll
    for (int h = 0; h < 2; ++h)
#pragma unroll
        for (int kk = 0; kk < 2; ++kk)
            qf[h][kk] = *(const f16x8*)(Qh + (size_t)(q0 + w * 32 + h * 16 + m) * DH +
                                        kk * 32 + g * 8);

    // mask C-init for tile 0, register-prefetched
    f32x4 mv[4];
#pragma unroll
    for (int kt = 0; kt < 4; ++kt)
        mv[kt] = *(const f32x4*)&mwb[kb0 + kt * 16 + g * 4];

    float m_r[2] = {-INFINITY, -INFINITY}, l_r[2] = {0.f, 0.f};
    f32x4 oacc[2][4] = {};

    unsigned* Pw = &Ps[w][0];
    const int ms = m & 7;

    for (int it = 0; it < KVS / 64; ++it) {
        const int t0 = kb0 + it * 64;
        const int p  = it & 1;
        const bool more = (it + 1 < KVS / 64);
        __syncthreads();   // tile t0 landed

        f32x4 mvn[4];
        if (more) {
            const int tn = t0 + 64;
            async16(&Ks[p ^ 1][ldsA], Kh + (size_t)tn * DH + gK0);
            async16(&Ks[p ^ 1][ldsB], Kh + (size_t)tn * DH + gK1);
            async16(&VTs[p ^ 1][ldsA], VTh + tn + gV0);
            async16(&VTs[p ^ 1][ldsB], VTh + tn + gV1);
            // prefetch next tile's mask into registers (off critical path)
#pragma unroll
            for (int kt = 0; kt < 4; ++kt)
                mvn[kt] = *(const f32x4*)&mwb[tn + kt * 16 + g * 4];
        }

        // ---- S^T = K Q^T + mask; each kf read feeds both q-halves ----
        f32x4 sacc[2][4];
#pragma unroll
        for (int kt = 0; kt < 4; ++kt) {
            sacc[0][kt] = mv[kt];
            sacc[1][kt] = mv[kt];
        }
#pragma unroll
        for (int kk = 0; kk < 2; ++kk) {
            const int slot = ((kk * 4 + g) ^ ms) * 8;
#pragma unroll
            for (int kt = 0; kt < 4; ++kt) {
                f16x8 kf = *(const f16x8*)&Ks[p][(kt * 16 + m) * 64 + slot];
                sacc[0][kt] = MFMA16(kf, qf[0][kk], sacc[0][kt]);
                sacc[1][kt] = MFMA16(kf, qf[1][kk], sacc[1][kt]);
            }
        }

        // ---- online softmax per half (sequential: sacc[h] dies as used) ----
        float lmax[2];
#pragma unroll
        for (int h = 0; h < 2; ++h) {
            const float x0 = m3(sacc[h][0][0], sacc[h][0][1], sacc[h][0][2]);
            const float x1 = m3(sacc[h][0][3], sacc[h][1][0], sacc[h][1][1]);
            const float x2 = m3(sacc[h][1][2], sacc[h][1][3], sacc[h][2][0]);
            const float x3 = m3(sacc[h][2][1], sacc[h][2][2], sacc[h][2][3]);
            const float x4 = m3(sacc[h][3][0], sacc[h][3][1], sacc[h][3][2]);
            lmax[h] = fmaxf(m3(x0, x1, x2), m3(x3, x4, sacc[h][3][3]));
        }

        // defer-max, lane-local check (row max = max of 4 lane maxes ->
        // all-lanes-in-bound implies all rows in bound; P <= 2^8, f16-safe)
        if (!__all(lmax[0] <= m_r[0] + 8.f && lmax[1] <= m_r[1] + 8.f)) {
#pragma unroll
            for (int h = 0; h < 2; ++h) {
                float r = fmaxf(lmax[h], __shfl_xor(lmax[h], 16));
                r = fmaxf(r, __shfl_xor(r, 32));
                const float mnew  = fmaxf(m_r[h], r);
                const float alpha = EXP2(m_r[h] - mnew);   // first tile: 0
                m_r[h] = mnew;
                l_r[h] *= alpha;
#pragma unroll
                for (int dt = 0; dt < 4; ++dt)
#pragma unroll
                    for (int r4 = 0; r4 < 4; ++r4) oacc[h][dt][r4] *= alpha;
            }
        }

        // ---- P = exp2(S - m); pack; stage to wave-private LDS rows h*16+m ----
#pragma unroll
        for (int h = 0; h < 2; ++h) {
            const int pwr = (h * 16 + m) * PSTR + g * 2;
            const f32x4 mh = {m_r[h], m_r[h], m_r[h], m_r[h]};
            float ps0 = 0.f, ps1 = 0.f;
#pragma unroll
            for (int kt = 0; kt < 4; ++kt) {
                const f32x4 d = sacc[h][kt] - mh;   // packed v_pk_add_f32
                const float p0 = EXP2(d[0]);
                const float p1 = EXP2(d[1]);
                const float p2 = EXP2(d[2]);
                const float p3 = EXP2(d[3]);
                const unsigned u0 = pk_f16(p0, p1);
                const unsigned u1 = pk_f16(p2, p3);
                *(uint2*)&Pw[pwr + kt * 8] = make_uint2(u0, u1);   // ds_write_b64
                if (kt < 2) {
                    ps0 = dot2acc(u0, ps0);
                    ps0 = dot2acc(u1, ps0);
                } else {
                    ps1 = dot2acc(u0, ps1);
                    ps1 = dot2acc(u1, ps1);
                }
            }
            l_r[h] += ps0 + ps1;
        }

        // ---- O^T += V^T P^T ; each vf read feeds both q-halves ----
#pragma unroll
        for (int kk = 0; kk < 2; ++kk) {
            union { uint4 u4; f16x8 h; } pf[2];
#pragma unroll
            for (int h = 0; h < 2; ++h)
                pf[h].u4 = *(const uint4*)&Pw[(h * 16 + m) * PSTR + kk * 16 + g * 4];
            const int slot = ((kk * 4 + g) ^ ms) * 8;
#pragma unroll
            for (int dt = 0; dt < 4; ++dt) {
                f16x8 vf = *(const f16x8*)&VTs[p][(dt * 16 + m) * 64 + slot];
                oacc[0][dt] = MFMA16(vf, pf[0].h, oacc[0][dt]);
                oacc[1][dt] = MFMA16(vf, pf[1].h, oacc[1][dt]);
            }
        }

        if (more) {
#pragma unroll
            for (int kt = 0; kt < 4; ++kt) mv[kt] = mvn[kt];
        }
    }

    // ---- final l reduction + per-split-normalized partial store ----
#pragma unroll
    for (int h = 0; h < 2; ++h) {
        float lv = l_r[h];
        lv += __shfl_xor(lv, 16);
        lv += __shfl_xor(lv, 32);
        const float inv = 1.0f / lv;
        const int q = q0 + w * 32 + h * 16 + m;
        const size_t rowi = ((size_t)z * NB * NH + bh) * SEQ + q;
        _Float16* Orow = Op + rowi * DH;
#pragma unroll
        for (int dt = 0; dt < 4; ++dt) {
            _Float16 o4[4] = { (_Float16)(oacc[h][dt][0] * inv),
                               (_Float16)(oacc[h][dt][1] * inv),
                               (_Float16)(oacc[h][dt][2] * inv),
                               (_Float16)(oacc[h][dt][3] * inv) };
            *(uint2*)(Orow + dt * 16 + g * 4) = *(const uint2*)o4;
        }
        if (g == 0) ((float2*)Ml)[rowi] = make_float2(m_r[h], lv);
    }
}

// ---------------------------------------------------------------------------
// Combine the 2 KV-splits: O = (a0*O0n + a1*O1n) / (a0+a1),
// a_z = exp2(m_z - M) * l_z  (exact, defer-max-safe). 16 threads per q-row,
// 4 d each. grid (RH*16/256) x 256. Writes Ows f16 [B,S,512].
// ---------------------------------------------------------------------------
__global__ __launch_bounds__(256) void combine(const _Float16* __restrict__ Op,
                                               const float* __restrict__ Ml,
                                               _Float16* __restrict__ O)
{
    const int i = blockIdx.x * 256 + threadIdx.x;
    const int r = i >> 4;            // bh*SEQ + q
    const int dq = (i & 15) * 4;
    const float2 ml0 = ((const float2*)Ml)[r];
    const float2 ml1 = ((const float2*)Ml)[RH + r];
    const float M = fmaxf(ml0.x, ml1.x);
    float a0 = EXP2(ml0.x - M) * ml0.y;
    float a1 = EXP2(ml1.x - M) * ml1.y;
    const float inv = 1.f / (a0 + a1);
    a0 *= inv; a1 *= inv;
    union { uint2 u; _Float16 h[4]; } v0, v1, o;
    v0.u = *(const uint2*)(Op + (size_t)r * DH + dq);
    v1.u = *(const uint2*)(Op + ((size_t)RH + r) * DH + dq);
#pragma unroll
    for (int j = 0; j < 4; ++j)
        o.h[j] = (_Float16)(a0 * (float)v0.h[j] + a1 * (float)v1.h[j]);
    const int bh = r >> 12, q = r & (SEQ - 1);
    const int b = bh >> 3, h = bh & 7;
    *(uint2*)(O + ((size_t)b * SEQ + q) * DM + h * DH + dq) = o.u;
}

extern "C" void kernel_launch(void* const* d_in, const int* in_sizes, int n_in,
                              void* d_out, int out_size, void* d_ws, size_t ws_size,
                              hipStream_t stream) {
    const float* q    = (const float*)d_in[0];
    const float* k    = (const float*)d_in[1];
    const float* v    = (const float*)d_in[2];
    const float* mask = (const float*)d_in[3];
    const float* wq   = (const float*)d_in[4];
    const float* bq   = (const float*)d_in[5];
    const float* wk   = (const float*)d_in[6];
    const float* bk   = (const float*)d_in[7];
    const float* wv   = (const float*)d_in[8];
    const float* bv   = (const float*)d_in[9];
    const float* wo   = (const float*)d_in[10];
    const float* bo   = (const float*)d_in[11];

    // workspace (~59 MB): Wt 2MB | mw 32KB | scratch 24MB | Qws,Kws,VTws,Ows
    // (cvt_qkv removed: proj3 reads q/k/v fp32 directly; the old Qin/Kin/Vin
    // slots are now pure scratch for the flash partials Opart (16MB) + Ml.)
    const size_t P8 = (size_t)MR * DM;
    _Float16* Wt  = (_Float16*)d_ws;
    float*    mw  = (float*)(Wt + (size_t)4 * DM * DM);
    _Float16* Sc0 = (_Float16*)(mw + NB * SEQ);   // 24MB scratch (3x P8)
    _Float16* Qws = Sc0 + 3 * P8;
    _Float16* Kws = Qws + P8;
    _Float16* VTws = Kws + P8;
    _Float16* Ows  = VTws + P8;

    _Float16* Opart = Sc0;               // 2*RH*64 f16 = 16 MB
    float*    Mlb   = (float*)(Sc0 + 2 * P8);   // 1 MB

    cvt_w<<<dim3(8, 8, 4), 256, 0, stream>>>(wq, wk, wv, wo, Wt);
    maskprep<<<dim3(NB * SEQ / 256), 256, 0, stream>>>(mask, mw);

    proj3<<<dim3(MR / 128, DM / 64, 3), 256, 0, stream>>>(
        q, k, v, Wt, bq, bk, bv, Qws, Kws, VTws);

    flash_mfma<<<dim3(SEQ / 128, NB * NH, NSPL), 256, 0, stream>>>(
        Qws, Kws, VTws, mw, Opart, Mlb);

    combine<<<dim3(RH * 16 / 256), 256, 0, stream>>>(Opart, Mlb, Ows);

    gemm_out<<<dim3(MR / 128, DM / 64), 256, 0, stream>>>(
        Ows, Wt + (size_t)3 * DM * DM, bo, (float*)d_out);
}

// Round 11
// 257.458 us; speedup vs baseline: 1.0096x; 1.0096x over previous
//
#include <hip/hip_runtime.h>

// MultiHeadAttention: B=2, S=4096, D=512, H=8, depth=64. fp32 in/out.
// mfma_f32_16x16x32_f16 everywhere, fp32 accum. S^T = K Q^T flash (one q-row
// per lane), async double-buffered global_load_lds staging in ALL matmul
// kernels. Round 22: reverted to the R8 configuration (best measured, 250.3us
// -- R9's NSPL=4 and R10's cvt_qkv-into-proj3 fusion both regressed at the
// pipeline level; proj3 re-reads each X panel 8x so fp32 reg-staging
// amplified traffic 2x8-fold). Single new edit: maskprep folded into flash's
// register mask-prefetch (scale by -1e9*log2e applied at load, fully hidden
// behind MFMAs; identical fp32 numerics) -- one fewer kernel. Flash:
// QBLK=32, wave-private P-LDS, XCD-bijective swizzle, mask reg-prefetch,
// defer-max (THR=8, lane-local), v_max3 tree, dot2 psum. NSPL=2.
#define NH   8
#define DH   64
#define NB   2
#define SEQ  4096
#define DM   512
#define MR   (NB * SEQ)
#define LSTR 72
#define LOG2E 1.44269504089f
#define MSCALE (-1e9f * LOG2E)
#define NSPL 2
#define KVS  (SEQ / NSPL)
#define RH   (NB * NH * SEQ)   // 65536 q-rows across heads/splits
#define PSTR 36                // P_lds row stride in u32 (even, mult of 4)

using f16x8 = __attribute__((ext_vector_type(8))) _Float16;
using f32x4 = __attribute__((ext_vector_type(4))) float;
using h2    = __attribute__((ext_vector_type(2))) _Float16;
#define MFMA16(a, b, c) __builtin_amdgcn_mfma_f32_16x16x32_f16(a, b, c, 0, 0, 0)

#if defined(__has_builtin) && __has_builtin(__builtin_amdgcn_exp2f)
#define EXP2(x) __builtin_amdgcn_exp2f(x)
#else
extern "C" __device__ float __ocml_native_exp2_f32(float);
#define EXP2(x) __ocml_native_exp2_f32(x)
#endif

__device__ __forceinline__ unsigned pk_f16(float a, float b) {
    typedef __fp16 fp16v2 __attribute__((ext_vector_type(2)));
    union { fp16v2 h; unsigned u; } c;
    c.h = __builtin_amdgcn_cvt_pkrtz(a, b);
    return c.u;
}
__device__ __forceinline__ float m3(float a, float b, float c) {
    return fmaxf(fmaxf(a, b), c);   // fuses to v_max3_f32
}
// l-sum accumulate from a packed f16 pair: c += p.lo + p.hi
__device__ __forceinline__ float dot2acc(unsigned u, float c) {
#if defined(__has_builtin) && __has_builtin(__builtin_amdgcn_fdot2)
    h2 a = __builtin_bit_cast(h2, u);
    h2 one = {(_Float16)1.f, (_Float16)1.f};
    return __builtin_amdgcn_fdot2(a, one, c, false);
#else
    h2 a = __builtin_bit_cast(h2, u);
    return c + (float)a[0] + (float)a[1];
#endif
}
// async 16B/lane global -> LDS (lds dest = wave-uniform base + lane*16)
__device__ __forceinline__ void async16(void* lds, const void* g) {
    __builtin_amdgcn_global_load_lds(
        (__attribute__((address_space(1))) void*)g,
        (__attribute__((address_space(3))) void*)lds, 16, 0, 0);
}

// ---------------------------------------------------------------------------
// W fp32 [k][n] -> Wt f16 [n][k], 4 weights. grid (8,8,4) x 256.
// ---------------------------------------------------------------------------
__global__ __launch_bounds__(256) void cvt_w(
    const float* __restrict__ w0, const float* __restrict__ w1,
    const float* __restrict__ w2, const float* __restrict__ w3,
    _Float16* __restrict__ Wt)
{
    __shared__ _Float16 T[64 * LSTR];
    const int z = blockIdx.z;
    const float* W = (z == 0) ? w0 : (z == 1 ? w1 : (z == 2 ? w2 : w3));
    _Float16* out = Wt + (size_t)z * DM * DM;
    const int t = threadIdx.x;
    const int k0 = blockIdx.x * 64, n0 = blockIdx.y * 64;
#pragma unroll
    for (int i = 0; i < 4; ++i) {
        const int kl  = i * 16 + (t >> 4);
        const int nl4 = (t & 15) * 4;
        float4 u = *(const float4*)(W + (size_t)(k0 + kl) * DM + n0 + nl4);
        T[(nl4 + 0) * LSTR + kl] = (_Float16)u.x;
        T[(nl4 + 1) * LSTR + kl] = (_Float16)u.y;
        T[(nl4 + 2) * LSTR + kl] = (_Float16)u.z;
        T[(nl4 + 3) * LSTR + kl] = (_Float16)u.w;
    }
    __syncthreads();
#pragma unroll
    for (int i = 0; i < 2; ++i) {
        const int nl = i * 32 + (t >> 3);
        const int kc = (t & 7) * 8;
        *(uint4*)(out + (size_t)(n0 + nl) * DM + k0 + kc) = *(const uint4*)&T[nl * LSTR + kc];
    }
}

// q,k,v fp32 -> f16 flat [MR][DM]. grid 6144 x 256, 8 elems/thread.
__global__ __launch_bounds__(256) void cvt_qkv(
    const float* __restrict__ q, const float* __restrict__ k,
    const float* __restrict__ v,
    _Float16* __restrict__ Qo, _Float16* __restrict__ Ko, _Float16* __restrict__ Vo)
{
    const size_t PER = (size_t)MR * DM;
    size_t base = ((size_t)blockIdx.x * 256 + threadIdx.x) * 8;
    const int tz = (int)(base / PER);
    const size_t off = base % PER;
    const float* s = (tz == 0) ? q : (tz == 1 ? k : v);
    _Float16* d    = (tz == 0) ? Qo : (tz == 1 ? Ko : Vo);
    float4 a = *(const float4*)(s + off);
    float4 b = *(const float4*)(s + off + 4);
    uint4 p = make_uint4(pk_f16(a.x, a.y), pk_f16(a.z, a.w),
                         pk_f16(b.x, b.y), pk_f16(b.z, b.w));
    *(uint4*)(d + off) = p;
}

// ---------------------------------------------------------------------------
// Fused QKV projection, async double-buffered. X f16 [M][512] by z;
// Wt f16 [3][n][k]. z<2: head-split f16 [B,H,S,64] (Q scaled by log2e);
// z==2: transposed [B,H,64,S]. grid (MR/128, 8, 3), block 256.
// LDS swizzle: chunk c -> row c>>3, slot c&7; data for column-chunk
// ((c&7)^(row&7)) stored there (swizzle applied on the global address side).
// ---------------------------------------------------------------------------
__global__ __launch_bounds__(256) void proj3(
    const _Float16* __restrict__ Qin, const _Float16* __restrict__ Kin,
    const _Float16* __restrict__ Vin, const _Float16* __restrict__ Wt,
    const float* __restrict__ bq, const float* __restrict__ bk,
    const float* __restrict__ bv,
    _Float16* __restrict__ Qo, _Float16* __restrict__ Ko,
    _Float16* __restrict__ VTo)
{
    __shared__ _Float16 Xs[2][128 * 64];
    __shared__ _Float16 Ws[2][64 * 64];

    const int z = blockIdx.z;
    const _Float16* X = (z == 0) ? Qin : (z == 1 ? Kin : Vin);
    const _Float16* W = Wt + (size_t)z * DM * DM;
    const float* bias = (z == 0) ? bq : (z == 1 ? bk : bv);
    const float scale = (z == 0) ? LOG2E : 1.0f;

    const int t = threadIdx.x;
    const int l = t & 63, w = t >> 6;
    const int m = l & 15, g = l >> 4;
    const int ms = m & 7;
    const int row0 = blockIdx.x * 128;
    const int col0 = blockIdx.y * 64;

    int xr[4], xsw[4];
#pragma unroll
    for (int i = 0; i < 4; ++i) {
        const int c = w * 256 + i * 64 + l;
        xr[i]  = c >> 3;
        xsw[i] = ((c & 7) ^ (xr[i] & 7)) * 8;
    }
    int wr[2], wsw[2];
#pragma unroll
    for (int i = 0; i < 2; ++i) {
        const int c = w * 128 + i * 64 + l;
        wr[i]  = c >> 3;
        wsw[i] = ((c & 7) ^ (wr[i] & 7)) * 8;
    }

    // prologue: k0 = 0 into buffer 0
#pragma unroll
    for (int i = 0; i < 4; ++i)
        async16(&Xs[0][(w * 256 + i * 64) * 8], X + (size_t)(row0 + xr[i]) * DM + xsw[i]);
#pragma unroll
    for (int i = 0; i < 2; ++i)
        async16(&Ws[0][(w * 128 + i * 64) * 8], W + (size_t)(col0 + wr[i]) * DM + wsw[i]);

    f32x4 acc[2][4] = {};

    for (int k0 = 0; k0 < DM; k0 += 64) {
        const int p = (k0 >> 6) & 1;
        __syncthreads();   // drains tile k0 (issued a full compute-phase ago)
        if (k0 + 64 < DM) {
            const int kn = k0 + 64;
#pragma unroll
            for (int i = 0; i < 4; ++i)
                async16(&Xs[p ^ 1][(w * 256 + i * 64) * 8],
                        X + (size_t)(row0 + xr[i]) * DM + kn + xsw[i]);
#pragma unroll
            for (int i = 0; i < 2; ++i)
                async16(&Ws[p ^ 1][(w * 128 + i * 64) * 8],
                        W + (size_t)(col0 + wr[i]) * DM + kn + wsw[i]);
        }
#pragma unroll
        for (int kk = 0; kk < 2; ++kk) {
            const int slot = ((kk * 4 + g) ^ ms) * 8;
            f16x8 a0 = *(const f16x8*)&Xs[p][(w * 32 + m) * 64 + slot];
            f16x8 a1 = *(const f16x8*)&Xs[p][(w * 32 + 16 + m) * 64 + slot];
#pragma unroll
            for (int ct = 0; ct < 4; ++ct) {
                f16x8 bf = *(const f16x8*)&Ws[p][(ct * 16 + m) * 64 + slot];
                acc[0][ct] = MFMA16(a0, bf, acc[0][ct]);
                acc[1][ct] = MFMA16(a1, bf, acc[1][ct]);
            }
        }
    }

    float bv4[4];
#pragma unroll
    for (int ct = 0; ct < 4; ++ct) bv4[ct] = bias[col0 + ct * 16 + m];

    if (z == 2) {
        __syncthreads();   // all waves done reading Xs
        _Float16* T = &Xs[0][0];   // reuse as T[64][136]
#pragma unroll
        for (int rt = 0; rt < 2; ++rt)
#pragma unroll
            for (int reg = 0; reg < 4; ++reg) {
                const int s_l = w * 32 + rt * 16 + g * 4 + reg;
#pragma unroll
                for (int ct = 0; ct < 4; ++ct) {
                    const int d = ct * 16 + m;
                    T[d * 136 + s_l] = (_Float16)(acc[rt][ct][reg] + bv4[ct]);
                }
            }
        __syncthreads();
        const int bb = row0 >> 12;
        const int s0 = row0 & (SEQ - 1);
#pragma unroll
        for (int j = 0; j < 4; ++j) {
            const int c = j * 256 + t;
            const int d = c >> 4;
            const int sc = (c & 15) * 8;
            *(uint4*)(VTo + (((size_t)bb * NH + blockIdx.y) * DH + d) * SEQ + s0 + sc) =
                *(const uint4*)&T[d * 136 + sc];
        }
    } else {
        _Float16* out = (z == 0) ? Qo : Ko;
#pragma unroll
        for (int rt = 0; rt < 2; ++rt)
#pragma unroll
            for (int reg = 0; reg < 4; ++reg) {
                const int row = row0 + w * 32 + rt * 16 + g * 4 + reg;
                const int bb = row >> 12;
                const int s  = row & (SEQ - 1);
#pragma unroll
                for (int ct = 0; ct < 4; ++ct)
                    out[(((size_t)bb * NH + blockIdx.y) * SEQ + s) * DH + ct * 16 + m] =
                        (_Float16)(scale * (acc[rt][ct][reg] + bv4[ct]));
            }
    }
}

// ---------------------------------------------------------------------------
// Output GEMM: d_out[M,512] fp32 = Ows[M,512](f16) @ Wo + bo. Async dbuf.
// grid (MR/128, 8), block 256.
// ---------------------------------------------------------------------------
__global__ __launch_bounds__(256) void gemm_out(const _Float16* __restrict__ X,
                                                const _Float16* __restrict__ W,
                                                const float* __restrict__ bias,
                                                float* __restrict__ out)
{
    __shared__ _Float16 Xs[2][128 * 64];
    __shared__ _Float16 Ws[2][64 * 64];

    const int t = threadIdx.x;
    const int l = t & 63, w = t >> 6;
    const int m = l & 15, g = l >> 4;
    const int ms = m & 7;
    const int row0 = blockIdx.x * 128;
    const int col0 = blockIdx.y * 64;

    int xr[4], xsw[4];
#pragma unroll
    for (int i = 0; i < 4; ++i) {
        const int c = w * 256 + i * 64 + l;
        xr[i]  = c >> 3;
        xsw[i] = ((c & 7) ^ (xr[i] & 7)) * 8;
    }
    int wr[2], wsw[2];
#pragma unroll
    for (int i = 0; i < 2; ++i) {
        const int c = w * 128 + i * 64 + l;
        wr[i]  = c >> 3;
        wsw[i] = ((c & 7) ^ (wr[i] & 7)) * 8;
    }

#pragma unroll
    for (int i = 0; i < 4; ++i)
        async16(&Xs[0][(w * 256 + i * 64) * 8], X + (size_t)(row0 + xr[i]) * DM + xsw[i]);
#pragma unroll
    for (int i = 0; i < 2; ++i)
        async16(&Ws[0][(w * 128 + i * 64) * 8], W + (size_t)(col0 + wr[i]) * DM + wsw[i]);

    f32x4 acc[2][4] = {};

    for (int k0 = 0; k0 < DM; k0 += 64) {
        const int p = (k0 >> 6) & 1;
        __syncthreads();
        if (k0 + 64 < DM) {
            const int kn = k0 + 64;
#pragma unroll
            for (int i = 0; i < 4; ++i)
                async16(&Xs[p ^ 1][(w * 256 + i * 64) * 8],
                        X + (size_t)(row0 + xr[i]) * DM + kn + xsw[i]);
#pragma unroll
            for (int i = 0; i < 2; ++i)
                async16(&Ws[p ^ 1][(w * 128 + i * 64) * 8],
                        W + (size_t)(col0 + wr[i]) * DM + kn + wsw[i]);
        }
#pragma unroll
        for (int kk = 0; kk < 2; ++kk) {
            const int slot = ((kk * 4 + g) ^ ms) * 8;
            f16x8 a0 = *(const f16x8*)&Xs[p][(w * 32 + m) * 64 + slot];
            f16x8 a1 = *(const f16x8*)&Xs[p][(w * 32 + 16 + m) * 64 + slot];
#pragma unroll
            for (int ct = 0; ct < 4; ++ct) {
                f16x8 bf = *(const f16x8*)&Ws[p][(ct * 16 + m) * 64 + slot];
                acc[0][ct] = MFMA16(a0, bf, acc[0][ct]);
                acc[1][ct] = MFMA16(a1, bf, acc[1][ct]);
            }
        }
    }

    float bv4[4];
#pragma unroll
    for (int ct = 0; ct < 4; ++ct) bv4[ct] = bias[col0 + ct * 16 + m];

#pragma unroll
    for (int rt = 0; rt < 2; ++rt)
#pragma unroll
        for (int reg = 0; reg < 4; ++reg) {
            const int row = row0 + w * 32 + rt * 16 + g * 4 + reg;
#pragma unroll
            for (int ct = 0; ct < 4; ++ct)
                out[(size_t)row * DM + col0 + ct * 16 + m] = acc[rt][ct][reg] + bv4[ct];
        }
}

// ---------------------------------------------------------------------------
// Flash attention, KV-split x2, 32 q-rows per wave (two 16-row halves).
// Q(log2e-scaled),K f16 [B*H,S,64]; VT f16 [B*H,64,S]; mask fp32 [B][S]
// (RAW mask; the -1e9*log2e scale is applied during the register prefetch,
// replacing the old maskprep pre-pass -- identical fp32 numerics).
// Split z covers kv in [z*2048, z*2048+2048); writes per-split-NORMALIZED
// partial Op f16 [z][bh][q][64] plus Ml f32x2 {m,l}. grid (S/128, B*H, 2)
// with XCD-bijective swizzle: flat w -> o=(w&7)*128 + w>>3, so the 32
// q-blocks sharing one (bh,z) K/V panel (512KB, L2-resident) run on ONE
// XCD. Every K/V LDS fragment read feeds TWO MFMAs (one per q-half); PV
// B-frags via wave-private P staging in LDS. __launch_bounds__(256,3).
// ---------------------------------------------------------------------------
__global__ __launch_bounds__(256, 3) void flash_mfma(
    const _Float16* __restrict__ Q, const _Float16* __restrict__ K,
    const _Float16* __restrict__ VT, const float* __restrict__ mask,
    _Float16* __restrict__ Op, float* __restrict__ Ml)
{
    __shared__ _Float16 Ks [2][64 * 64];
    __shared__ _Float16 VTs[2][64 * 64];
    __shared__ unsigned Ps[4][32 * PSTR];   // per-wave P pairs: [q-row][pair]

    const int t = threadIdx.x;
    const int l = t & 63, w = t >> 6;
    const int m = l & 15, g = l >> 4;

    // XCD-bijective swizzle (1024 blocks, 1024 % 8 == 0)
    const unsigned wfl = blockIdx.x + 32u * blockIdx.y + 512u * blockIdx.z;
    const unsigned o   = (wfl & 7u) * 128u + (wfl >> 3);
    const int q0 = (int)(o & 31u) * 128;
    const int bh = (int)(o >> 5) & 15;
    const int z  = (int)(o >> 9);
    const int b  = bh >> 3;
    const int kb0 = z * KVS;

    const _Float16* Qh  = Q  + (size_t)bh * SEQ * DH;
    const _Float16* Kh  = K  + (size_t)bh * SEQ * DH;
    const _Float16* VTh = VT + (size_t)bh * DH * SEQ;
    const float* mwb = mask + (size_t)b * SEQ;

    const int c0 = w * 128 + l, c1 = c0 + 64;
    const int r0 = c0 >> 3,     r1 = c1 >> 3;
    const int cl0 = (c0 & 7) ^ (r0 & 7), cl1 = (c1 & 7) ^ (r1 & 7);
    const int    gK0 = r0 * DH + cl0 * 8, gK1 = r1 * DH + cl1 * 8;
    const size_t gV0 = (size_t)r0 * SEQ + cl0 * 8, gV1 = (size_t)r1 * SEQ + cl1 * 8;
    const int ldsA = w * 1024, ldsB = ldsA + 512;

    async16(&Ks[0][ldsA], Kh + (size_t)kb0 * DH + gK0);
    async16(&Ks[0][ldsB], Kh + (size_t)kb0 * DH + gK1);
    async16(&VTs[0][ldsA], VTh + kb0 + gV0);
    async16(&VTs[0][ldsB], VTh + kb0 + gV1);

    // Q fragments in registers: wave w covers q-rows q0 + w*32 + {0..15,16..31}
    f16x8 qf[2][2];
#pragma unroll
    for (int h = 0; h < 2; ++h)
#pragma unroll
        for (int kk = 0; kk < 2; ++kk)
            qf[h][kk] = *(const f16x8*)(Qh + (size_t)(q0 + w * 32 + h * 16 + m) * DH +
                                        kk * 32 + g * 8);

    // mask C-init for tile 0, register-prefetched + scaled (maskprep fused)
    f32x4 mv[4];
#pragma unroll
    for (int kt = 0; kt < 4; ++kt) {
        f32x4 raw = *(const f32x4*)&mwb[kb0 + kt * 16 + g * 4];
        mv[kt] = raw * MSCALE;
    }

    float m_r[2] = {-INFINITY, -INFINITY}, l_r[2] = {0.f, 0.f};
    f32x4 oacc[2][4] = {};

    unsigned* Pw = &Ps[w][0];
    const int ms = m & 7;

    for (int it = 0; it < KVS / 64; ++it) {
        const int t0 = kb0 + it * 64;
        const int p  = it & 1;
        const bool more = (it + 1 < KVS / 64);
        __syncthreads();   // tile t0 landed

        f32x4 mvn[4];
        if (more) {
            const int tn = t0 + 64;
            async16(&Ks[p ^ 1][ldsA], Kh + (size_t)tn * DH + gK0);
            async16(&Ks[p ^ 1][ldsB], Kh + (size_t)tn * DH + gK1);
            async16(&VTs[p ^ 1][ldsA], VTh + tn + gV0);
            async16(&VTs[p ^ 1][ldsB], VTh + tn + gV1);
            // prefetch + scale next tile's mask (off critical path)
#pragma unroll
            for (int kt = 0; kt < 4; ++kt) {
                f32x4 raw = *(const f32x4*)&mwb[tn + kt * 16 + g * 4];
                mvn[kt] = raw * MSCALE;
            }
        }

        // ---- S^T = K Q^T + mask; each kf read feeds both q-halves ----
        f32x4 sacc[2][4];
#pragma unroll
        for (int kt = 0; kt < 4; ++kt) {
            sacc[0][kt] = mv[kt];
            sacc[1][kt] = mv[kt];
        }
#pragma unroll
        for (int kk = 0; kk < 2; ++kk) {
            const int slot = ((kk * 4 + g) ^ ms) * 8;
#pragma unroll
            for (int kt = 0; kt < 4; ++kt) {
                f16x8 kf = *(const f16x8*)&Ks[p][(kt * 16 + m) * 64 + slot];
                sacc[0][kt] = MFMA16(kf, qf[0][kk], sacc[0][kt]);
                sacc[1][kt] = MFMA16(kf, qf[1][kk], sacc[1][kt]);
            }
        }

        // ---- online softmax per half (sequential: sacc[h] dies as used) ----
        float lmax[2];
#pragma unroll
        for (int h = 0; h < 2; ++h) {
            const float x0 = m3(sacc[h][0][0], sacc[h][0][1], sacc[h][0][2]);
            const float x1 = m3(sacc[h][0][3], sacc[h][1][0], sacc[h][1][1]);
            const float x2 = m3(sacc[h][1][2], sacc[h][1][3], sacc[h][2][0]);
            const float x3 = m3(sacc[h][2][1], sacc[h][2][2], sacc[h][2][3]);
            const float x4 = m3(sacc[h][3][0], sacc[h][3][1], sacc[h][3][2]);
            lmax[h] = fmaxf(m3(x0, x1, x2), m3(x3, x4, sacc[h][3][3]));
        }

        // defer-max, lane-local check (row max = max of 4 lane maxes ->
        // all-lanes-in-bound implies all rows in bound; P <= 2^8, f16-safe)
        if (!__all(lmax[0] <= m_r[0] + 8.f && lmax[1] <= m_r[1] + 8.f)) {
#pragma unroll
            for (int h = 0; h < 2; ++h) {
                float r = fmaxf(lmax[h], __shfl_xor(lmax[h], 16));
                r = fmaxf(r, __shfl_xor(r, 32));
                const float mnew  = fmaxf(m_r[h], r);
                const float alpha = EXP2(m_r[h] - mnew);   // first tile: 0
                m_r[h] = mnew;
                l_r[h] *= alpha;
#pragma unroll
                for (int dt = 0; dt < 4; ++dt)
#pragma unroll
                    for (int r4 = 0; r4 < 4; ++r4) oacc[h][dt][r4] *= alpha;
            }
        }

        // ---- P = exp2(S - m); pack; stage to wave-private LDS rows h*16+m ----
#pragma unroll
        for (int h = 0; h < 2; ++h) {
            const int pwr = (h * 16 + m) * PSTR + g * 2;
            const f32x4 mh = {m_r[h], m_r[h], m_r[h], m_r[h]};
            float ps0 = 0.f, ps1 = 0.f;
#pragma unroll
            for (int kt = 0; kt < 4; ++kt) {
                const f32x4 d = sacc[h][kt] - mh;   // packed v_pk_add_f32
                const float p0 = EXP2(d[0]);
                const float p1 = EXP2(d[1]);
                const float p2 = EXP2(d[2]);
                const float p3 = EXP2(d[3]);
                const unsigned u0 = pk_f16(p0, p1);
                const unsigned u1 = pk_f16(p2, p3);
                *(uint2*)&Pw[pwr + kt * 8] = make_uint2(u0, u1);   // ds_write_b64
                if (kt < 2) {
                    ps0 = dot2acc(u0, ps0);
                    ps0 = dot2acc(u1, ps0);
                } else {
                    ps1 = dot2acc(u0, ps1);
                    ps1 = dot2acc(u1, ps1);
                }
            }
            l_r[h] += ps0 + ps1;
        }

        // ---- O^T += V^T P^T ; each vf read feeds both q-halves ----
#pragma unroll
        for (int kk = 0; kk < 2; ++kk) {
            union { uint4 u4; f16x8 h; } pf[2];
#pragma unroll
            for (int h = 0; h < 2; ++h)
                pf[h].u4 = *(const uint4*)&Pw[(h * 16 + m) * PSTR + kk * 16 + g * 4];
            const int slot = ((kk * 4 + g) ^ ms) * 8;
#pragma unroll
            for (int dt = 0; dt < 4; ++dt) {
                f16x8 vf = *(const f16x8*)&VTs[p][(dt * 16 + m) * 64 + slot];
                oacc[0][dt] = MFMA16(vf, pf[0].h, oacc[0][dt]);
                oacc[1][dt] = MFMA16(vf, pf[1].h, oacc[1][dt]);
            }
        }

        if (more) {
#pragma unroll
            for (int kt = 0; kt < 4; ++kt) mv[kt] = mvn[kt];
        }
    }

    // ---- final l reduction + per-split-normalized partial store ----
#pragma unroll
    for (int h = 0; h < 2; ++h) {
        float lv = l_r[h];
        lv += __shfl_xor(lv, 16);
        lv += __shfl_xor(lv, 32);
        const float inv = 1.0f / lv;
        const int q = q0 + w * 32 + h * 16 + m;
        const size_t rowi = ((size_t)z * NB * NH + bh) * SEQ + q;
        _Float16* Orow = Op + rowi * DH;
#pragma unroll
        for (int dt = 0; dt < 4; ++dt) {
            _Float16 o4[4] = { (_Float16)(oacc[h][dt][0] * inv),
                               (_Float16)(oacc[h][dt][1] * inv),
                               (_Float16)(oacc[h][dt][2] * inv),
                               (_Float16)(oacc[h][dt][3] * inv) };
            *(uint2*)(Orow + dt * 16 + g * 4) = *(const uint2*)o4;
        }
        if (g == 0) ((float2*)Ml)[rowi] = make_float2(m_r[h], lv);
    }
}

// ---------------------------------------------------------------------------
// Combine the 2 KV-splits: O = (a0*O0n + a1*O1n) / (a0+a1),
// a_z = exp2(m_z - M) * l_z  (exact, defer-max-safe). 16 threads per q-row,
// 4 d each. grid (RH*16/256) x 256. Writes Ows f16 [B,S,512].
// ---------------------------------------------------------------------------
__global__ __launch_bounds__(256) void combine(const _Float16* __restrict__ Op,
                                               const float* __restrict__ Ml,
                                               _Float16* __restrict__ O)
{
    const int i = blockIdx.x * 256 + threadIdx.x;
    const int r = i >> 4;            // bh*SEQ + q
    const int dq = (i & 15) * 4;
    const float2 ml0 = ((const float2*)Ml)[r];
    const float2 ml1 = ((const float2*)Ml)[RH + r];
    const float M = fmaxf(ml0.x, ml1.x);
    float a0 = EXP2(ml0.x - M) * ml0.y;
    float a1 = EXP2(ml1.x - M) * ml1.y;
    const float inv = 1.f / (a0 + a1);
    a0 *= inv; a1 *= inv;
    union { uint2 u; _Float16 h[4]; } v0, v1, o;
    v0.u = *(const uint2*)(Op + (size_t)r * DH + dq);
    v1.u = *(const uint2*)(Op + ((size_t)RH + r) * DH + dq);
#pragma unroll
    for (int j = 0; j < 4; ++j)
        o.h[j] = (_Float16)(a0 * (float)v0.h[j] + a1 * (float)v1.h[j]);
    const int bh = r >> 12, q = r & (SEQ - 1);
    const int b = bh >> 3, h = bh & 7;
    *(uint2*)(O + ((size_t)b * SEQ + q) * DM + h * DH + dq) = o.u;
}

extern "C" void kernel_launch(void* const* d_in, const int* in_sizes, int n_in,
                              void* d_out, int out_size, void* d_ws, size_t ws_size,
                              hipStream_t stream) {
    const float* q    = (const float*)d_in[0];
    const float* k    = (const float*)d_in[1];
    const float* v    = (const float*)d_in[2];
    const float* mask = (const float*)d_in[3];
    const float* wq   = (const float*)d_in[4];
    const float* bq   = (const float*)d_in[5];
    const float* wk   = (const float*)d_in[6];
    const float* bk   = (const float*)d_in[7];
    const float* wv   = (const float*)d_in[8];
    const float* bv   = (const float*)d_in[9];
    const float* wo   = (const float*)d_in[10];
    const float* bo   = (const float*)d_in[11];

    // workspace (~59 MB): Wt 2MB | pad 32KB | Qin,Kin,Vin f16 | Qws,Kws,VTws,Ows
    // After proj3, Qin/Kin/Vin are dead: Opart (16MB) reuses Qin+Kin exactly,
    // Ml (1MB) reuses Vin. (maskprep fused into flash; pad slot unused.)
    const size_t P8 = (size_t)MR * DM;
    _Float16* Wt  = (_Float16*)d_ws;
    float*    pad = (float*)(Wt + (size_t)4 * DM * DM);
    _Float16* Qin = (_Float16*)(pad + NB * SEQ);
    _Float16* Kin = Qin + P8;
    _Float16* Vin = Kin + P8;
    _Float16* Qws = Vin + P8;
    _Float16* Kws = Qws + P8;
    _Float16* VTws = Kws + P8;
    _Float16* Ows  = VTws + P8;

    _Float16* Opart = Qin;          // 2*16*4096*64 f16 = 16 MB (spans Qin+Kin)
    float*    Mlb   = (float*)Vin;  // 2*65536*2 f32 = 1 MB

    cvt_w<<<dim3(8, 8, 4), 256, 0, stream>>>(wq, wk, wv, wo, Wt);
    cvt_qkv<<<dim3(3 * (MR * DM / 8) / 256), 256, 0, stream>>>(q, k, v, Qin, Kin, Vin);

    proj3<<<dim3(MR / 128, DM / 64, 3), 256, 0, stream>>>(
        Qin, Kin, Vin, Wt, bq, bk, bv, Qws, Kws, VTws);

    flash_mfma<<<dim3(SEQ / 128, NB * NH, NSPL), 256, 0, stream>>>(
        Qws, Kws, VTws, mask, Opart, Mlb);

    combine<<<dim3(RH * 16 / 256), 256, 0, stream>>>(Opart, Mlb, Ows);

    gemm_out<<<dim3(MR / 128, DM / 64), 256, 0, stream>>>(
        Ows, Wt + (size_t)3 * DM * DM, bo, (float*)d_out);
}

// Round 12
// 247.064 us; speedup vs baseline: 1.0520x; 1.0421x over previous
//
#include <hip/hip_runtime.h>

// MultiHeadAttention: B=2, S=4096, D=512, H=8, depth=64. fp32 in/out.
// mfma_f32_16x16x32_f16 everywhere, fp32 accum. S^T = K Q^T flash (one q-row
// per lane), async double-buffered global_load_lds staging in the GEMMs.
// Round 23: flash K/V staging switched from double- to SINGLE-buffered with
// two barriers per tile (barrier A: tile landed; barrier B: all reads done,
// then issue next-tile async16). LDS 51.2KB -> 34.8KB, so ALL 4 blocks/CU
// (grid 1024 = exactly 4/CU) are co-resident: +33% waves and no 1-block
// tail. Intra-block dbuf latency hiding is replaced by inter-block overlap.
// Fragment addressing, wave-private P-LDS, XCD-bijective swizzle, fused
// mask scale (maskprep-free), defer-max (THR=8, lane-local), v_max3 tree,
// dot2 psum all unchanged from R8/R11. NSPL=2, QBLK=32.
#define NH   8
#define DH   64
#define NB   2
#define SEQ  4096
#define DM   512
#define MR   (NB * SEQ)
#define LSTR 72
#define LOG2E 1.44269504089f
#define MSCALE (-1e9f * LOG2E)
#define NSPL 2
#define KVS  (SEQ / NSPL)
#define RH   (NB * NH * SEQ)   // 65536 q-rows across heads/splits
#define PSTR 36                // P_lds row stride in u32 (even, mult of 4)

using f16x8 = __attribute__((ext_vector_type(8))) _Float16;
using f32x4 = __attribute__((ext_vector_type(4))) float;
using h2    = __attribute__((ext_vector_type(2))) _Float16;
#define MFMA16(a, b, c) __builtin_amdgcn_mfma_f32_16x16x32_f16(a, b, c, 0, 0, 0)

#if defined(__has_builtin) && __has_builtin(__builtin_amdgcn_exp2f)
#define EXP2(x) __builtin_amdgcn_exp2f(x)
#else
extern "C" __device__ float __ocml_native_exp2_f32(float);
#define EXP2(x) __ocml_native_exp2_f32(x)
#endif

__device__ __forceinline__ unsigned pk_f16(float a, float b) {
    typedef __fp16 fp16v2 __attribute__((ext_vector_type(2)));
    union { fp16v2 h; unsigned u; } c;
    c.h = __builtin_amdgcn_cvt_pkrtz(a, b);
    return c.u;
}
__device__ __forceinline__ float m3(float a, float b, float c) {
    return fmaxf(fmaxf(a, b), c);   // fuses to v_max3_f32
}
// l-sum accumulate from a packed f16 pair: c += p.lo + p.hi
__device__ __forceinline__ float dot2acc(unsigned u, float c) {
#if defined(__has_builtin) && __has_builtin(__builtin_amdgcn_fdot2)
    h2 a = __builtin_bit_cast(h2, u);
    h2 one = {(_Float16)1.f, (_Float16)1.f};
    return __builtin_amdgcn_fdot2(a, one, c, false);
#else
    h2 a = __builtin_bit_cast(h2, u);
    return c + (float)a[0] + (float)a[1];
#endif
}
// async 16B/lane global -> LDS (lds dest = wave-uniform base + lane*16)
__device__ __forceinline__ void async16(void* lds, const void* g) {
    __builtin_amdgcn_global_load_lds(
        (__attribute__((address_space(1))) void*)g,
        (__attribute__((address_space(3))) void*)lds, 16, 0, 0);
}

// ---------------------------------------------------------------------------
// W fp32 [k][n] -> Wt f16 [n][k], 4 weights. grid (8,8,4) x 256.
// ---------------------------------------------------------------------------
__global__ __launch_bounds__(256) void cvt_w(
    const float* __restrict__ w0, const float* __restrict__ w1,
    const float* __restrict__ w2, const float* __restrict__ w3,
    _Float16* __restrict__ Wt)
{
    __shared__ _Float16 T[64 * LSTR];
    const int z = blockIdx.z;
    const float* W = (z == 0) ? w0 : (z == 1 ? w1 : (z == 2 ? w2 : w3));
    _Float16* out = Wt + (size_t)z * DM * DM;
    const int t = threadIdx.x;
    const int k0 = blockIdx.x * 64, n0 = blockIdx.y * 64;
#pragma unroll
    for (int i = 0; i < 4; ++i) {
        const int kl  = i * 16 + (t >> 4);
        const int nl4 = (t & 15) * 4;
        float4 u = *(const float4*)(W + (size_t)(k0 + kl) * DM + n0 + nl4);
        T[(nl4 + 0) * LSTR + kl] = (_Float16)u.x;
        T[(nl4 + 1) * LSTR + kl] = (_Float16)u.y;
        T[(nl4 + 2) * LSTR + kl] = (_Float16)u.z;
        T[(nl4 + 3) * LSTR + kl] = (_Float16)u.w;
    }
    __syncthreads();
#pragma unroll
    for (int i = 0; i < 2; ++i) {
        const int nl = i * 32 + (t >> 3);
        const int kc = (t & 7) * 8;
        *(uint4*)(out + (size_t)(n0 + nl) * DM + k0 + kc) = *(const uint4*)&T[nl * LSTR + kc];
    }
}

// q,k,v fp32 -> f16 flat [MR][DM]. grid 6144 x 256, 8 elems/thread.
__global__ __launch_bounds__(256) void cvt_qkv(
    const float* __restrict__ q, const float* __restrict__ k,
    const float* __restrict__ v,
    _Float16* __restrict__ Qo, _Float16* __restrict__ Ko, _Float16* __restrict__ Vo)
{
    const size_t PER = (size_t)MR * DM;
    size_t base = ((size_t)blockIdx.x * 256 + threadIdx.x) * 8;
    const int tz = (int)(base / PER);
    const size_t off = base % PER;
    const float* s = (tz == 0) ? q : (tz == 1 ? k : v);
    _Float16* d    = (tz == 0) ? Qo : (tz == 1 ? Ko : Vo);
    float4 a = *(const float4*)(s + off);
    float4 b = *(const float4*)(s + off + 4);
    uint4 p = make_uint4(pk_f16(a.x, a.y), pk_f16(a.z, a.w),
                         pk_f16(b.x, b.y), pk_f16(b.z, b.w));
    *(uint4*)(d + off) = p;
}

// ---------------------------------------------------------------------------
// Fused QKV projection, async double-buffered. X f16 [M][512] by z;
// Wt f16 [3][n][k]. z<2: head-split f16 [B,H,S,64] (Q scaled by log2e);
// z==2: transposed [B,H,64,S]. grid (MR/128, 8, 3), block 256.
// LDS swizzle: chunk c -> row c>>3, slot c&7; data for column-chunk
// ((c&7)^(row&7)) stored there (swizzle applied on the global address side).
// ---------------------------------------------------------------------------
__global__ __launch_bounds__(256) void proj3(
    const _Float16* __restrict__ Qin, const _Float16* __restrict__ Kin,
    const _Float16* __restrict__ Vin, const _Float16* __restrict__ Wt,
    const float* __restrict__ bq, const float* __restrict__ bk,
    const float* __restrict__ bv,
    _Float16* __restrict__ Qo, _Float16* __restrict__ Ko,
    _Float16* __restrict__ VTo)
{
    __shared__ _Float16 Xs[2][128 * 64];
    __shared__ _Float16 Ws[2][64 * 64];

    const int z = blockIdx.z;
    const _Float16* X = (z == 0) ? Qin : (z == 1 ? Kin : Vin);
    const _Float16* W = Wt + (size_t)z * DM * DM;
    const float* bias = (z == 0) ? bq : (z == 1 ? bk : bv);
    const float scale = (z == 0) ? LOG2E : 1.0f;

    const int t = threadIdx.x;
    const int l = t & 63, w = t >> 6;
    const int m = l & 15, g = l >> 4;
    const int ms = m & 7;
    const int row0 = blockIdx.x * 128;
    const int col0 = blockIdx.y * 64;

    int xr[4], xsw[4];
#pragma unroll
    for (int i = 0; i < 4; ++i) {
        const int c = w * 256 + i * 64 + l;
        xr[i]  = c >> 3;
        xsw[i] = ((c & 7) ^ (xr[i] & 7)) * 8;
    }
    int wr[2], wsw[2];
#pragma unroll
    for (int i = 0; i < 2; ++i) {
        const int c = w * 128 + i * 64 + l;
        wr[i]  = c >> 3;
        wsw[i] = ((c & 7) ^ (wr[i] & 7)) * 8;
    }

    // prologue: k0 = 0 into buffer 0
#pragma unroll
    for (int i = 0; i < 4; ++i)
        async16(&Xs[0][(w * 256 + i * 64) * 8], X + (size_t)(row0 + xr[i]) * DM + xsw[i]);
#pragma unroll
    for (int i = 0; i < 2; ++i)
        async16(&Ws[0][(w * 128 + i * 64) * 8], W + (size_t)(col0 + wr[i]) * DM + wsw[i]);

    f32x4 acc[2][4] = {};

    for (int k0 = 0; k0 < DM; k0 += 64) {
        const int p = (k0 >> 6) & 1;
        __syncthreads();   // drains tile k0 (issued a full compute-phase ago)
        if (k0 + 64 < DM) {
            const int kn = k0 + 64;
#pragma unroll
            for (int i = 0; i < 4; ++i)
                async16(&Xs[p ^ 1][(w * 256 + i * 64) * 8],
                        X + (size_t)(row0 + xr[i]) * DM + kn + xsw[i]);
#pragma unroll
            for (int i = 0; i < 2; ++i)
                async16(&Ws[p ^ 1][(w * 128 + i * 64) * 8],
                        W + (size_t)(col0 + wr[i]) * DM + kn + wsw[i]);
        }
#pragma unroll
        for (int kk = 0; kk < 2; ++kk) {
            const int slot = ((kk * 4 + g) ^ ms) * 8;
            f16x8 a0 = *(const f16x8*)&Xs[p][(w * 32 + m) * 64 + slot];
            f16x8 a1 = *(const f16x8*)&Xs[p][(w * 32 + 16 + m) * 64 + slot];
#pragma unroll
            for (int ct = 0; ct < 4; ++ct) {
                f16x8 bf = *(const f16x8*)&Ws[p][(ct * 16 + m) * 64 + slot];
                acc[0][ct] = MFMA16(a0, bf, acc[0][ct]);
                acc[1][ct] = MFMA16(a1, bf, acc[1][ct]);
            }
        }
    }

    float bv4[4];
#pragma unroll
    for (int ct = 0; ct < 4; ++ct) bv4[ct] = bias[col0 + ct * 16 + m];

    if (z == 2) {
        __syncthreads();   // all waves done reading Xs
        _Float16* T = &Xs[0][0];   // reuse as T[64][136]
#pragma unroll
        for (int rt = 0; rt < 2; ++rt)
#pragma unroll
            for (int reg = 0; reg < 4; ++reg) {
                const int s_l = w * 32 + rt * 16 + g * 4 + reg;
#pragma unroll
                for (int ct = 0; ct < 4; ++ct) {
                    const int d = ct * 16 + m;
                    T[d * 136 + s_l] = (_Float16)(acc[rt][ct][reg] + bv4[ct]);
                }
            }
        __syncthreads();
        const int bb = row0 >> 12;
        const int s0 = row0 & (SEQ - 1);
#pragma unroll
        for (int j = 0; j < 4; ++j) {
            const int c = j * 256 + t;
            const int d = c >> 4;
            const int sc = (c & 15) * 8;
            *(uint4*)(VTo + (((size_t)bb * NH + blockIdx.y) * DH + d) * SEQ + s0 + sc) =
                *(const uint4*)&T[d * 136 + sc];
        }
    } else {
        _Float16* out = (z == 0) ? Qo : Ko;
#pragma unroll
        for (int rt = 0; rt < 2; ++rt)
#pragma unroll
            for (int reg = 0; reg < 4; ++reg) {
                const int row = row0 + w * 32 + rt * 16 + g * 4 + reg;
                const int bb = row >> 12;
                const int s  = row & (SEQ - 1);
#pragma unroll
                for (int ct = 0; ct < 4; ++ct)
                    out[(((size_t)bb * NH + blockIdx.y) * SEQ + s) * DH + ct * 16 + m] =
                        (_Float16)(scale * (acc[rt][ct][reg] + bv4[ct]));
            }
    }
}

// ---------------------------------------------------------------------------
// Output GEMM: d_out[M,512] fp32 = Ows[M,512](f16) @ Wo + bo. Async dbuf.
// grid (MR/128, 8), block 256.
// ---------------------------------------------------------------------------
__global__ __launch_bounds__(256) void gemm_out(const _Float16* __restrict__ X,
                                                const _Float16* __restrict__ W,
                                                const float* __restrict__ bias,
                                                float* __restrict__ out)
{
    __shared__ _Float16 Xs[2][128 * 64];
    __shared__ _Float16 Ws[2][64 * 64];

    const int t = threadIdx.x;
    const int l = t & 63, w = t >> 6;
    const int m = l & 15, g = l >> 4;
    const int ms = m & 7;
    const int row0 = blockIdx.x * 128;
    const int col0 = blockIdx.y * 64;

    int xr[4], xsw[4];
#pragma unroll
    for (int i = 0; i < 4; ++i) {
        const int c = w * 256 + i * 64 + l;
        xr[i]  = c >> 3;
        xsw[i] = ((c & 7) ^ (xr[i] & 7)) * 8;
    }
    int wr[2], wsw[2];
#pragma unroll
    for (int i = 0; i < 2; ++i) {
        const int c = w * 128 + i * 64 + l;
        wr[i]  = c >> 3;
        wsw[i] = ((c & 7) ^ (wr[i] & 7)) * 8;
    }

#pragma unroll
    for (int i = 0; i < 4; ++i)
        async16(&Xs[0][(w * 256 + i * 64) * 8], X + (size_t)(row0 + xr[i]) * DM + xsw[i]);
#pragma unroll
    for (int i = 0; i < 2; ++i)
        async16(&Ws[0][(w * 128 + i * 64) * 8], W + (size_t)(col0 + wr[i]) * DM + wsw[i]);

    f32x4 acc[2][4] = {};

    for (int k0 = 0; k0 < DM; k0 += 64) {
        const int p = (k0 >> 6) & 1;
        __syncthreads();
        if (k0 + 64 < DM) {
            const int kn = k0 + 64;
#pragma unroll
            for (int i = 0; i < 4; ++i)
                async16(&Xs[p ^ 1][(w * 256 + i * 64) * 8],
                        X + (size_t)(row0 + xr[i]) * DM + kn + xsw[i]);
#pragma unroll
            for (int i = 0; i < 2; ++i)
                async16(&Ws[p ^ 1][(w * 128 + i * 64) * 8],
                        W + (size_t)(col0 + wr[i]) * DM + kn + wsw[i]);
        }
#pragma unroll
        for (int kk = 0; kk < 2; ++kk) {
            const int slot = ((kk * 4 + g) ^ ms) * 8;
            f16x8 a0 = *(const f16x8*)&Xs[p][(w * 32 + m) * 64 + slot];
            f16x8 a1 = *(const f16x8*)&Xs[p][(w * 32 + 16 + m) * 64 + slot];
#pragma unroll
            for (int ct = 0; ct < 4; ++ct) {
                f16x8 bf = *(const f16x8*)&Ws[p][(ct * 16 + m) * 64 + slot];
                acc[0][ct] = MFMA16(a0, bf, acc[0][ct]);
                acc[1][ct] = MFMA16(a1, bf, acc[1][ct]);
            }
        }
    }

    float bv4[4];
#pragma unroll
    for (int ct = 0; ct < 4; ++ct) bv4[ct] = bias[col0 + ct * 16 + m];

#pragma unroll
    for (int rt = 0; rt < 2; ++rt)
#pragma unroll
        for (int reg = 0; reg < 4; ++reg) {
            const int row = row0 + w * 32 + rt * 16 + g * 4 + reg;
#pragma unroll
            for (int ct = 0; ct < 4; ++ct)
                out[(size_t)row * DM + col0 + ct * 16 + m] = acc[rt][ct][reg] + bv4[ct];
        }
}

// ---------------------------------------------------------------------------
// Flash attention, KV-split x2, 32 q-rows per wave (two 16-row halves).
// Q(log2e-scaled),K f16 [B*H,S,64]; VT f16 [B*H,64,S]; mask fp32 [B][S]
// (raw; -1e9*log2e applied during the register prefetch).
// SINGLE-buffered K/V staging, two barriers per tile:
//   barrier A -> tile t in LDS -> QK^T, softmax, P-stage, PV ->
//   barrier B -> issue async16 for t+1 (+ mask prefetch).
// LDS = 8K (Ks) + 8K (VTs) + 18K (Ps) = 34.8KB -> 4 blocks/CU, and grid
// 1024 = exactly 4/CU: all blocks co-resident, no tail. Split z covers kv
// in [z*2048, z*2048+2048); per-split-NORMALIZED partial Op f16
// [z][bh][q][64] + Ml {m,l}. grid (S/128, B*H, 2), XCD-bijective swizzle
// (flat w -> (w&7)*128 + w>>3). Every K/V fragment read feeds TWO MFMAs;
// PV B-frags via wave-private P staging in LDS. __launch_bounds__(256,4).
// ---------------------------------------------------------------------------
__global__ __launch_bounds__(256, 4) void flash_mfma(
    const _Float16* __restrict__ Q, const _Float16* __restrict__ K,
    const _Float16* __restrict__ VT, const float* __restrict__ mask,
    _Float16* __restrict__ Op, float* __restrict__ Ml)
{
    __shared__ _Float16 Ks [64 * 64];
    __shared__ _Float16 VTs[64 * 64];
    __shared__ unsigned Ps[4][32 * PSTR];   // per-wave P pairs: [q-row][pair]

    const int t = threadIdx.x;
    const int l = t & 63, w = t >> 6;
    const int m = l & 15, g = l >> 4;

    // XCD-bijective swizzle (1024 blocks, 1024 % 8 == 0)
    const unsigned wfl = blockIdx.x + 32u * blockIdx.y + 512u * blockIdx.z;
    const unsigned o   = (wfl & 7u) * 128u + (wfl >> 3);
    const int q0 = (int)(o & 31u) * 128;
    const int bh = (int)(o >> 5) & 15;
    const int z  = (int)(o >> 9);
    const int b  = bh >> 3;
    const int kb0 = z * KVS;

    const _Float16* Qh  = Q  + (size_t)bh * SEQ * DH;
    const _Float16* Kh  = K  + (size_t)bh * SEQ * DH;
    const _Float16* VTh = VT + (size_t)bh * DH * SEQ;
    const float* mwb = mask + (size_t)b * SEQ;

    const int c0 = w * 128 + l, c1 = c0 + 64;
    const int r0 = c0 >> 3,     r1 = c1 >> 3;
    const int cl0 = (c0 & 7) ^ (r0 & 7), cl1 = (c1 & 7) ^ (r1 & 7);
    const int    gK0 = r0 * DH + cl0 * 8, gK1 = r1 * DH + cl1 * 8;
    const size_t gV0 = (size_t)r0 * SEQ + cl0 * 8, gV1 = (size_t)r1 * SEQ + cl1 * 8;
    const int ldsA = w * 1024, ldsB = ldsA + 512;

    // prologue: tile 0 loads into the single buffers
    async16(&Ks[ldsA], Kh + (size_t)kb0 * DH + gK0);
    async16(&Ks[ldsB], Kh + (size_t)kb0 * DH + gK1);
    async16(&VTs[ldsA], VTh + kb0 + gV0);
    async16(&VTs[ldsB], VTh + kb0 + gV1);

    // Q fragments in registers: wave w covers q-rows q0 + w*32 + {0..15,16..31}
    f16x8 qf[2][2];
#pragma unroll
    for (int h = 0; h < 2; ++h)
#pragma unroll
        for (int kk = 0; kk < 2; ++kk)
            qf[h][kk] = *(const f16x8*)(Qh + (size_t)(q0 + w * 32 + h * 16 + m) * DH +
                                        kk * 32 + g * 8);

    // mask C-init for tile 0, register-prefetched + scaled (maskprep fused)
    f32x4 mv[4];
#pragma unroll
    for (int kt = 0; kt < 4; ++kt) {
        f32x4 raw = *(const f32x4*)&mwb[kb0 + kt * 16 + g * 4];
        mv[kt] = raw * MSCALE;
    }

    float m_r[2] = {-INFINITY, -INFINITY}, l_r[2] = {0.f, 0.f};
    f32x4 oacc[2][4] = {};

    unsigned* Pw = &Ps[w][0];
    const int ms = m & 7;

    for (int it = 0; it < KVS / 64; ++it) {
        const int t0 = kb0 + it * 64;
        const bool more = (it + 1 < KVS / 64);
        __syncthreads();   // barrier A: tile t0 landed in Ks/VTs

        // ---- S^T = K Q^T + mask; each kf read feeds both q-halves ----
        f32x4 sacc[2][4];
#pragma unroll
        for (int kt = 0; kt < 4; ++kt) {
            sacc[0][kt] = mv[kt];
            sacc[1][kt] = mv[kt];
        }
#pragma unroll
        for (int kk = 0; kk < 2; ++kk) {
            const int slot = ((kk * 4 + g) ^ ms) * 8;
#pragma unroll
            for (int kt = 0; kt < 4; ++kt) {
                f16x8 kf = *(const f16x8*)&Ks[(kt * 16 + m) * 64 + slot];
                sacc[0][kt] = MFMA16(kf, qf[0][kk], sacc[0][kt]);
                sacc[1][kt] = MFMA16(kf, qf[1][kk], sacc[1][kt]);
            }
        }

        // ---- online softmax per half (sequential: sacc[h] dies as used) ----
        float lmax[2];
#pragma unroll
        for (int h = 0; h < 2; ++h) {
            const float x0 = m3(sacc[h][0][0], sacc[h][0][1], sacc[h][0][2]);
            const float x1 = m3(sacc[h][0][3], sacc[h][1][0], sacc[h][1][1]);
            const float x2 = m3(sacc[h][1][2], sacc[h][1][3], sacc[h][2][0]);
            const float x3 = m3(sacc[h][2][1], sacc[h][2][2], sacc[h][2][3]);
            const float x4 = m3(sacc[h][3][0], sacc[h][3][1], sacc[h][3][2]);
            lmax[h] = fmaxf(m3(x0, x1, x2), m3(x3, x4, sacc[h][3][3]));
        }

        // defer-max, lane-local check (row max = max of 4 lane maxes ->
        // all-lanes-in-bound implies all rows in bound; P <= 2^8, f16-safe)
        if (!__all(lmax[0] <= m_r[0] + 8.f && lmax[1] <= m_r[1] + 8.f)) {
#pragma unroll
            for (int h = 0; h < 2; ++h) {
                float r = fmaxf(lmax[h], __shfl_xor(lmax[h], 16));
                r = fmaxf(r, __shfl_xor(r, 32));
                const float mnew  = fmaxf(m_r[h], r);
                const float alpha = EXP2(m_r[h] - mnew);   // first tile: 0
                m_r[h] = mnew;
                l_r[h] *= alpha;
#pragma unroll
                for (int dt = 0; dt < 4; ++dt)
#pragma unroll
                    for (int r4 = 0; r4 < 4; ++r4) oacc[h][dt][r4] *= alpha;
            }
        }

        // ---- P = exp2(S - m); pack; stage to wave-private LDS rows h*16+m ----
#pragma unroll
        for (int h = 0; h < 2; ++h) {
            const int pwr = (h * 16 + m) * PSTR + g * 2;
            const f32x4 mh = {m_r[h], m_r[h], m_r[h], m_r[h]};
            float ps0 = 0.f, ps1 = 0.f;
#pragma unroll
            for (int kt = 0; kt < 4; ++kt) {
                const f32x4 d = sacc[h][kt] - mh;   // packed v_pk_add_f32
                const float p0 = EXP2(d[0]);
                const float p1 = EXP2(d[1]);
                const float p2 = EXP2(d[2]);
                const float p3 = EXP2(d[3]);
                const unsigned u0 = pk_f16(p0, p1);
                const unsigned u1 = pk_f16(p2, p3);
                *(uint2*)&Pw[pwr + kt * 8] = make_uint2(u0, u1);   // ds_write_b64
                if (kt < 2) {
                    ps0 = dot2acc(u0, ps0);
                    ps0 = dot2acc(u1, ps0);
                } else {
                    ps1 = dot2acc(u0, ps1);
                    ps1 = dot2acc(u1, ps1);
                }
            }
            l_r[h] += ps0 + ps1;
        }

        // ---- O^T += V^T P^T ; each vf read feeds both q-halves ----
#pragma unroll
        for (int kk = 0; kk < 2; ++kk) {
            union { uint4 u4; f16x8 h; } pf[2];
#pragma unroll
            for (int h = 0; h < 2; ++h)
                pf[h].u4 = *(const uint4*)&Pw[(h * 16 + m) * PSTR + kk * 16 + g * 4];
            const int slot = ((kk * 4 + g) ^ ms) * 8;
#pragma unroll
            for (int dt = 0; dt < 4; ++dt) {
                f16x8 vf = *(const f16x8*)&VTs[(dt * 16 + m) * 64 + slot];
                oacc[0][dt] = MFMA16(vf, pf[0].h, oacc[0][dt]);
                oacc[1][dt] = MFMA16(vf, pf[1].h, oacc[1][dt]);
            }
        }

        if (more) {
            __syncthreads();   // barrier B: all waves done reading Ks/VTs
            const int tn = t0 + 64;
            async16(&Ks[ldsA], Kh + (size_t)tn * DH + gK0);
            async16(&Ks[ldsB], Kh + (size_t)tn * DH + gK1);
            async16(&VTs[ldsA], VTh + tn + gV0);
            async16(&VTs[ldsB], VTh + tn + gV1);
            // next tile's mask into registers (drained by barrier A anyway)
#pragma unroll
            for (int kt = 0; kt < 4; ++kt) {
                f32x4 raw = *(const f32x4*)&mwb[tn + kt * 16 + g * 4];
                mv[kt] = raw * MSCALE;
            }
        }
    }

    // ---- final l reduction + per-split-normalized partial store ----
#pragma unroll
    for (int h = 0; h < 2; ++h) {
        float lv = l_r[h];
        lv += __shfl_xor(lv, 16);
        lv += __shfl_xor(lv, 32);
        const float inv = 1.0f / lv;
        const int q = q0 + w * 32 + h * 16 + m;
        const size_t rowi = ((size_t)z * NB * NH + bh) * SEQ + q;
        _Float16* Orow = Op + rowi * DH;
#pragma unroll
        for (int dt = 0; dt < 4; ++dt) {
            _Float16 o4[4] = { (_Float16)(oacc[h][dt][0] * inv),
                               (_Float16)(oacc[h][dt][1] * inv),
                               (_Float16)(oacc[h][dt][2] * inv),
                               (_Float16)(oacc[h][dt][3] * inv) };
            *(uint2*)(Orow + dt * 16 + g * 4) = *(const uint2*)o4;
        }
        if (g == 0) ((float2*)Ml)[rowi] = make_float2(m_r[h], lv);
    }
}

// ---------------------------------------------------------------------------
// Combine the 2 KV-splits: O = (a0*O0n + a1*O1n) / (a0+a1),
// a_z = exp2(m_z - M) * l_z  (exact, defer-max-safe). 16 threads per q-row,
// 4 d each. grid (RH*16/256) x 256. Writes Ows f16 [B,S,512].
// ---------------------------------------------------------------------------
__global__ __launch_bounds__(256) void combine(const _Float16* __restrict__ Op,
                                               const float* __restrict__ Ml,
                                               _Float16* __restrict__ O)
{
    const int i = blockIdx.x * 256 + threadIdx.x;
    const int r = i >> 4;            // bh*SEQ + q
    const int dq = (i & 15) * 4;
    const float2 ml0 = ((const float2*)Ml)[r];
    const float2 ml1 = ((const float2*)Ml)[RH + r];
    const float M = fmaxf(ml0.x, ml1.x);
    float a0 = EXP2(ml0.x - M) * ml0.y;
    float a1 = EXP2(ml1.x - M) * ml1.y;
    const float inv = 1.f / (a0 + a1);
    a0 *= inv; a1 *= inv;
    union { uint2 u; _Float16 h[4]; } v0, v1, o;
    v0.u = *(const uint2*)(Op + (size_t)r * DH + dq);
    v1.u = *(const uint2*)(Op + ((size_t)RH + r) * DH + dq);
#pragma unroll
    for (int j = 0; j < 4; ++j)
        o.h[j] = (_Float16)(a0 * (float)v0.h[j] + a1 * (float)v1.h[j]);
    const int bh = r >> 12, q = r & (SEQ - 1);
    const int b = bh >> 3, h = bh & 7;
    *(uint2*)(O + ((size_t)b * SEQ + q) * DM + h * DH + dq) = o.u;
}

extern "C" void kernel_launch(void* const* d_in, const int* in_sizes, int n_in,
                              void* d_out, int out_size, void* d_ws, size_t ws_size,
                              hipStream_t stream) {
    const float* q    = (const float*)d_in[0];
    const float* k    = (const float*)d_in[1];
    const float* v    = (const float*)d_in[2];
    const float* mask = (const float*)d_in[3];
    const float* wq   = (const float*)d_in[4];
    const float* bq   = (const float*)d_in[5];
    const float* wk   = (const float*)d_in[6];
    const float* bk   = (const float*)d_in[7];
    const float* wv   = (const float*)d_in[8];
    const float* bv   = (const float*)d_in[9];
    const float* wo   = (const float*)d_in[10];
    const float* bo   = (const float*)d_in[11];

    // workspace (~59 MB): Wt 2MB | pad 32KB | Qin,Kin,Vin f16 | Qws,Kws,VTws,Ows
    // After proj3, Qin/Kin/Vin are dead: Opart (16MB) reuses Qin+Kin exactly,
    // Ml (1MB) reuses Vin. (maskprep fused into flash; pad slot unused.)
    const size_t P8 = (size_t)MR * DM;
    _Float16* Wt  = (_Float16*)d_ws;
    float*    pad = (float*)(Wt + (size_t)4 * DM * DM);
    _Float16* Qin = (_Float16*)(pad + NB * SEQ);
    _Float16* Kin = Qin + P8;
    _Float16* Vin = Kin + P8;
    _Float16* Qws = Vin + P8;
    _Float16* Kws = Qws + P8;
    _Float16* VTws = Kws + P8;
    _Float16* Ows  = VTws + P8;

    _Float16* Opart = Qin;          // 2*16*4096*64 f16 = 16 MB (spans Qin+Kin)
    float*    Mlb   = (float*)Vin;  // 2*65536*2 f32 = 1 MB

    cvt_w<<<dim3(8, 8, 4), 256, 0, stream>>>(wq, wk, wv, wo, Wt);
    cvt_qkv<<<dim3(3 * (MR * DM / 8) / 256), 256, 0, stream>>>(q, k, v, Qin, Kin, Vin);

    proj3<<<dim3(MR / 128, DM / 64, 3), 256, 0, stream>>>(
        Qin, Kin, Vin, Wt, bq, bk, bv, Qws, Kws, VTws);

    flash_mfma<<<dim3(SEQ / 128, NB * NH, NSPL), 256, 0, stream>>>(
        Qws, Kws, VTws, mask, Opart, Mlb);

    combine<<<dim3(RH * 16 / 256), 256, 0, stream>>>(Opart, Mlb, Ows);

    gemm_out<<<dim3(MR / 128, DM / 64), 256, 0, stream>>>(
        Ows, Wt + (size_t)3 * DM * DM, bo, (float*)d_out);
}